// Round 6
// baseline (70.786 us; speedup 1.0000x reference)
//
#include <hip/hip_runtime.h>
#include <math.h>

// Problem constants (from reference)
#define FH 64    // feature map H (axis indexed by x)
#define FW 64    // feature map W (axis indexed by y)
#define FC 256   // channels
#define PP 7     // pool output dim
#define NROI 256
#define CHMAX 16 // max loads per memory round

__device__ __forceinline__ float4 fmax4(float4 a, float4 b) {
    return make_float4(fmaxf(a.x, b.x), fmaxf(a.y, b.y),
                       fmaxf(a.z, b.z), fmaxf(a.w, b.w));
}

// ---------------------------------------------------------------------------
// Warm pass: stream the whole featmap (4.2 MB) with grid-wide TLP so the
// HBM cold-miss latency is paid in a bandwidth-optimal kernel (~1-2 us)
// instead of inside the latency-critical gather. The 268 MB 0xAA poison
// before every timed iteration evicts L2+L3, so featmap is cold otherwise.
// Max-reduce + tiny d_ws write defeats dead-code elimination.
// ---------------------------------------------------------------------------
__global__ __launch_bounds__(256) void warm_kernel(
        const float4* __restrict__ feat,  // FH*FW*FC/4 float4s
        float4* __restrict__ ws)
{
    const int N = FH * FW * (FC / 4);     // 262144 float4s
    int tid = blockIdx.x * blockDim.x + threadIdx.x;
    const int stride = gridDim.x * blockDim.x;
    float4 m = make_float4(-INFINITY, -INFINITY, -INFINITY, -INFINITY);
    for (int p = tid; p < N; p += stride) m = fmax4(m, feat[p]);
    ws[tid] = m;
}

// CHK independent loads (offsets precomputed, tail slots duplicated) issued
// back-to-back, then one reduction pass. No address math between loads.
template <int CHK>
__device__ __forceinline__ float4 batch_max(const float4* __restrict__ base,
                                            const int* off, float4 acc) {
    float4 v[CHK];
#pragma unroll
    for (int u = 0; u < CHK; ++u) v[u] = base[off[u]];
#pragma unroll
    for (int u = 0; u < CHK; ++u) acc = fmax4(acc, v[u]);
    return acc;
}

// One 64-lane wave per output cell (r,i,j); lane = 4-channel group (float4),
// 1KB coalesced per load. Walk state wave-uniform (scalarized via
// readfirstlane; roi fetch is s_load). Input domain (0<=x1<x2<=1) makes the
// reference's clip() a no-op (max visited coord <= 63), so clamps dropped.
__global__ __launch_bounds__(256, 2) void roi_pool_kernel(
        const float* __restrict__ feat,   // (FH, FW, FC)
        const float* __restrict__ rois,   // (NROI, 4): x1,y1,x2,y2
        float* __restrict__ out)          // (NROI, PP, PP, FC)
{
    const int lane = threadIdx.x & 63;
    int cell = (blockIdx.x * blockDim.x + threadIdx.x) >> 6;
    cell = __builtin_amdgcn_readfirstlane(cell);   // wave-uniform -> SGPR

    const int j = cell % PP;
    const int t = cell / PP;
    const int i = t % PP;
    const int r = t / PP;

    const float4 roi = ((const float4*)rois)[r];   // uniform -> s_load_dwordx4

    int xlo = (int)floorf(roi.x * (float)FH);
    int xspan = (int)ceilf(roi.z * (float)FH) - xlo;
    xspan = xspan > 1 ? xspan : 1;
    int ylo = (int)floorf(roi.y * (float)FW);
    int yspan = (int)ceilf(roi.w * (float)FW) - ylo;
    yspan = yspan > 1 ? yspan : 1;

    // bin bounds (exact reference math; nonneg -> int div == floor)
    const int xs = xlo + (i * xspan) / PP;
    int xlen = (xlo + ((i + 1) * xspan + (PP - 1)) / PP) - xs;
    xlen = xlen > 1 ? xlen : 1;
    const int ys = ylo + (j * yspan) / PP;
    int ylen = (ylo + ((j + 1) * yspan + (PP - 1)) / PP) - ys;
    ylen = ylen > 1 ? ylen : 1;

    const float4* __restrict__ p =
        (const float4*)feat + (size_t)(xs * FW + ys) * (FC / 4) + lane;
    const int dnext = (FC / 4);                    // +1 pixel along y
    const int dwrap = (FW - ylen + 1) * (FC / 4);  // wrap to next x row

    float4 acc = make_float4(-INFINITY, -INFINITY, -INFINITY, -INFINITY);

    const int n = xlen * ylen;   // wave-uniform window size (<= 36 here)
    int cur = 0;                 // running offset (float4 units), uniform
    int sy = 0;                  // position within current y-run

    for (int q = 0; q < n; q += CHMAX) {
        const int m = n - q;     // pixels left in this round (uniform)
        int off[CHMAX];
        off[0] = cur;
#pragma unroll
        for (int u = 1; u < CHMAX; ++u) {
            if (u < m) {         // advance only while valid; else duplicate
                int wrap = (sy + 1 == ylen);
                cur += wrap ? dwrap : dnext;
                sy = wrap ? 0 : sy + 1;
            }
            off[u] = cur;
        }
        if (m <= 4)      acc = batch_max<4>(p, off, acc);
        else if (m <= 8) acc = batch_max<8>(p, off, acc);
        else             acc = batch_max<CHMAX>(p, off, acc);

        if (q + CHMAX < n) {     // step into next round's first pixel
            int wrap = (sy + 1 == ylen);
            cur += wrap ? dwrap : dnext;
            sy = wrap ? 0 : sy + 1;
        }
    }

    ((float4*)out)[(size_t)cell * (FC / 4) + lane] = acc;
}

extern "C" void kernel_launch(void* const* d_in, const int* in_sizes, int n_in,
                              void* d_out, int out_size, void* d_ws, size_t ws_size,
                              hipStream_t stream) {
    const float* feat = (const float*)d_in[0];   // (1,64,64,256)
    const float* rois = (const float*)d_in[1];   // (1,256,4)
    float* out = (float*)d_out;                  // (1,256,7,7,256)

    // Warm pass: pull featmap into L3/L2 with a streaming read (poison
    // evicted it). 256 blocks x 256 threads, 16B ws write per thread (1 MB).
    warm_kernel<<<256, 256, 0, stream>>>((const float4*)feat, (float4*)d_ws);

    const int total_threads = NROI * PP * PP * 64;  // one wave per cell
    const int block = 256;
    const int grid = (total_threads + block - 1) / block;  // 3136 exact
    roi_pool_kernel<<<grid, block, 0, stream>>>(feat, rois, out);
}